// Round 1
// baseline (72938.983 us; speedup 1.0000x reference)
//
#include <hip/hip_runtime.h>

#define D 896
#define NLAYER 24
#define HQ 14
#define HKV 2
#define DH 64
#define FFI 4864
#define BATCH 2
#define SEQ 2048
#define NTOK (BATCH*SEQ)
#define QKVN (HQ*DH + 2*HKV*DH)   /* 1152 */
#define KOFF (HQ*DH)              /* 896  */
#define VOFF (HQ*DH + HKV*DH)     /* 1024 */
#define GUN (2*FFI)               /* 9728 */

typedef unsigned short u16;
typedef unsigned int u32;
typedef __attribute__((ext_vector_type(8))) __bf16 bf16x8;
typedef __attribute__((ext_vector_type(4))) float f32x4;

__device__ __forceinline__ float bf2f(u16 u) {
  union { u32 u; float f; } v; v.u = ((u32)u) << 16; return v.f;
}
__device__ __forceinline__ u16 f2bf(float f) {
  union { float f; u32 u; } v; v.f = f;
  u32 r = v.u + 0x7fffu + ((v.u >> 16) & 1u);
  return (u16)(r >> 16);
}

// ---------------- RMSNorm: fp32 in -> bf16 out ----------------
__global__ __launch_bounds__(256) void rmsnorm_bf16_kernel(
    const float* __restrict__ x, const float* __restrict__ w, u16* __restrict__ out) {
  int row = blockIdx.x, t = threadIdx.x;
  const float* xr = x + (size_t)row * D;
  float4 xv = make_float4(0.f, 0.f, 0.f, 0.f);
  if (t < 224) xv = *(const float4*)(xr + t * 4);
  float ss = xv.x*xv.x + xv.y*xv.y + xv.z*xv.z + xv.w*xv.w;
  for (int off = 32; off > 0; off >>= 1) ss += __shfl_xor(ss, off);
  __shared__ float red[4];
  if ((t & 63) == 0) red[t >> 6] = ss;
  __syncthreads();
  float rstd = rsqrtf((red[0] + red[1] + red[2] + red[3]) * (1.0f / D) + 1e-6f);
  if (t < 224) {
    float4 wv = *(const float4*)(w + t * 4);
    u32 p0 = (u32)f2bf(xv.x*rstd*wv.x) | ((u32)f2bf(xv.y*rstd*wv.y) << 16);
    u32 p1 = (u32)f2bf(xv.z*rstd*wv.z) | ((u32)f2bf(xv.w*rstd*wv.w) << 16);
    uint2 ov; ov.x = p0; ov.y = p1;
    *(uint2*)(out + (size_t)row * D + t * 4) = ov;
  }
}

// ---------------- Final RMSNorm: fp32 in-place ----------------
__global__ __launch_bounds__(256) void rmsnorm_f32_kernel(
    float* __restrict__ x, const float* __restrict__ w) {
  int row = blockIdx.x, t = threadIdx.x;
  float* xr = x + (size_t)row * D;
  float4 xv = make_float4(0.f, 0.f, 0.f, 0.f);
  if (t < 224) xv = *(const float4*)(xr + t * 4);
  float ss = xv.x*xv.x + xv.y*xv.y + xv.z*xv.z + xv.w*xv.w;
  for (int off = 32; off > 0; off >>= 1) ss += __shfl_xor(ss, off);
  __shared__ float red[4];
  if ((t & 63) == 0) red[t >> 6] = ss;
  __syncthreads();
  float rstd = rsqrtf((red[0] + red[1] + red[2] + red[3]) * (1.0f / D) + 1e-6f);
  if (t < 224) {
    float4 wv = *(const float4*)(w + t * 4);
    float4 ov = make_float4(xv.x*rstd*wv.x, xv.y*rstd*wv.y, xv.z*rstd*wv.z, xv.w*rstd*wv.w);
    *(float4*)(xr + t * 4) = ov;
  }
}

// ------------- Transpose fp32 [R][C] -> bf16 [C][R] -------------
__global__ __launch_bounds__(256) void transpose_bf16_kernel(
    const float* __restrict__ src, u16* __restrict__ dst, int R, int C) {
  __shared__ float tile[32][33];
  int c0 = blockIdx.x * 32, r0 = blockIdx.y * 32;
  int tx = threadIdx.x & 31, ty = threadIdx.x >> 5;  // ty 0..7
  for (int i = 0; i < 4; ++i)
    tile[ty + i * 8][tx] = src[(size_t)(r0 + ty + i * 8) * C + c0 + tx];
  __syncthreads();
  for (int i = 0; i < 4; ++i)
    dst[(size_t)(c0 + ty + i * 8) * R + r0 + tx] = f2bf(tile[tx][ty + i * 8]);
}

// ---------------- GEMM: C[M,N] = A[M,K](bf16) @ Bt[N,K]^T(bf16) ----------------
// MODE 0: bf16 out (+optional bias b0)
// MODE 1: fp32 out += (residual add)
// MODE 2: bf16 out, fused-QKV 3-way bias (b0 cols<896, b1 <1024, b2 rest)
template <int MODE>
__global__ __launch_bounds__(256) void gemm_kernel(
    const u16* __restrict__ A, int lda, const u16* __restrict__ Bt,
    const float* __restrict__ b0, const float* __restrict__ b1, const float* __restrict__ b2,
    void* __restrict__ outp, int N, int K) {
  __shared__ __align__(16) u16 As[128 * 40];
  __shared__ __align__(16) u16 Bs[128 * 40];
  const int tid = threadIdx.x;
  const int lane = tid & 63, wid = tid >> 6;
  const int wm = wid >> 1, wn = wid & 1;
  const int quad = lane >> 4, l16 = lane & 15;
  const int m0 = blockIdx.x * 128, n0 = blockIdx.y * 128;
  const int r0 = tid >> 2, seg = tid & 3;

  f32x4 acc[4][4];
  for (int i = 0; i < 4; ++i)
    for (int j = 0; j < 4; ++j) acc[i][j] = (f32x4){0.f, 0.f, 0.f, 0.f};

  for (int kt = 0; kt < K; kt += 32) {
    for (int i = 0; i < 2; ++i) {
      int row = r0 + i * 64;
      *(uint4*)&As[row * 40 + seg * 8] =
          *(const uint4*)&A[(size_t)(m0 + row) * lda + kt + seg * 8];
      *(uint4*)&Bs[row * 40 + seg * 8] =
          *(const uint4*)&Bt[(size_t)(n0 + row) * K + kt + seg * 8];
    }
    __syncthreads();
    bf16x8 af[4], bf[4];
    for (int mi = 0; mi < 4; ++mi)
      af[mi] = *(const bf16x8*)&As[(wm * 64 + mi * 16 + l16) * 40 + quad * 8];
    for (int ni = 0; ni < 4; ++ni)
      bf[ni] = *(const bf16x8*)&Bs[(wn * 64 + ni * 16 + l16) * 40 + quad * 8];
    for (int mi = 0; mi < 4; ++mi)
      for (int ni = 0; ni < 4; ++ni)
        acc[mi][ni] = __builtin_amdgcn_mfma_f32_16x16x32_bf16(af[mi], bf[ni], acc[mi][ni], 0, 0, 0);
    __syncthreads();
  }

  for (int mi = 0; mi < 4; ++mi) {
    int rowb = m0 + wm * 64 + mi * 16 + quad * 4;
    for (int ni = 0; ni < 4; ++ni) {
      int col = n0 + wn * 64 + ni * 16 + l16;
      float bvv = 0.f;
      if (MODE == 0 && b0 != nullptr) bvv = b0[col];
      if (MODE == 2) bvv = (col < KOFF) ? b0[col] : (col < VOFF) ? b1[col - KOFF] : b2[col - VOFF];
      for (int r = 0; r < 4; ++r) {
        if (MODE == 1)
          ((float*)outp)[(size_t)(rowb + r) * N + col] += acc[mi][ni][r];
        else
          ((u16*)outp)[(size_t)(rowb + r) * N + col] = f2bf(acc[mi][ni][r] + bvv);
      }
    }
  }
}

// ---------------- RoPE in-place on bf16 (q or k region of fused qkv) ----------------
__global__ __launch_bounds__(256) void rope_kernel(
    u16* __restrict__ x, int H, int rowStride, int colOff, int total) {
  int gid = blockIdx.x * 256 + threadIdx.x;
  if (gid >= total) return;
  int i = gid & 31;
  int rem = gid >> 5;
  int h = rem % H;
  int tok = rem / H;
  int s = tok & (SEQ - 1);
  size_t base = (size_t)tok * rowStride + colOff + h * DH;
  float x1 = bf2f(x[base + i]), x2 = bf2f(x[base + i + 32]);
  float inv = exp2f((float)i * (-2.0f / DH) * 19.931568569324174f);  // theta^(-2i/DH)
  float ang = (float)s * inv;
  float c, sn;
  sincosf(ang, &sn, &c);
  x[base + i]      = f2bf(x1 * c - x2 * sn);
  x[base + i + 32] = f2bf(x2 * c + x1 * sn);
}

// ---------------- Attention: wave handles 4 q rows, online softmax ----------------
__global__ __launch_bounds__(256) void attn_kernel(
    const u16* __restrict__ qkv, const int* __restrict__ tt,
    const float* __restrict__ mask, u16* __restrict__ o) {
  const int tid = threadIdx.x, wid = tid >> 6, lane = tid & 63;
  const int b = blockIdx.z, h = blockIdx.y;
  const int hkv = h / (HQ / HKV);
  const int s0 = blockIdx.x * 16 + wid * 4;

  __shared__ __align__(16) u32 K2[32 * 64];      // [dpair][key]
  __shared__ __align__(16) u16 Vt[64 * 64];      // [key][d]
  __shared__ __align__(16) float qsp[4][32][8];  // [wave][dpair][lo r0..3 | hi r0..3]
  __shared__ __align__(16) float ps[4][64][4];   // [wave][key][row]

  const size_t rowbase = (size_t)b * SEQ;
  for (int r = 0; r < 4; ++r) {
    float qv = bf2f(qkv[(rowbase + s0 + r) * QKVN + h * DH + lane]) * 0.125f;
    qsp[wid][lane >> 1][(lane & 1) * 4 + r] = qv;
  }
  int tq[4];
  for (int r = 0; r < 4; ++r) tq[r] = tt[rowbase + s0 + r];
  float m_run[4], l_run[4], acc[4];
  for (int r = 0; r < 4; ++r) { m_run[r] = -3e38f; l_run[r] = 0.f; acc[r] = 0.f; }

  for (int kt = 0; kt < SEQ / 64; ++kt) {
    __syncthreads();
    for (int ii = 0; ii < 8; ++ii) {
      int idx = tid + ii * 256;
      int j = idx >> 5, dp = idx & 31;
      size_t rowoff = (rowbase + kt * 64 + j) * QKVN;
      K2[dp * 64 + j] = *(const u32*)&qkv[rowoff + KOFF + hkv * DH + dp * 2];
      *(u32*)&Vt[j * 64 + dp * 2] = *(const u32*)&qkv[rowoff + VOFF + hkv * DH + dp * 2];
    }
    int kidx = kt * 64 + lane;
    int tk = tt[rowbase + kidx];
    float mk = mask[rowbase + kidx];
    __syncthreads();

    // scores: lane = key
    float s[4] = {0.f, 0.f, 0.f, 0.f};
    for (int dp = 0; dp < 32; ++dp) {
      u32 kk = K2[dp * 64 + lane];
      float klo = bf2f((u16)(kk & 0xffffu)), khi = bf2f((u16)(kk >> 16));
      float4 qlo = *(const float4*)&qsp[wid][dp][0];
      float4 qhi = *(const float4*)&qsp[wid][dp][4];
      s[0] += qlo.x * klo + qhi.x * khi;
      s[1] += qlo.y * klo + qhi.y * khi;
      s[2] += qlo.z * klo + qhi.z * khi;
      s[3] += qlo.w * klo + qhi.w * khi;
    }
    for (int r = 0; r < 4; ++r) {
      int qi = s0 + r;
      bool allowed = (tq[r] == 0 && tk == 0) ||
                     (tq[r] == 1 && (tk == 0 || (tk == 1 && kidx <= qi)));
      float sv = (allowed && mk != 0.0f) ? s[r] : -3e38f;
      float mm = sv;
      for (int off = 32; off > 0; off >>= 1) mm = fmaxf(mm, __shfl_xor(mm, off));
      float mnew = fmaxf(m_run[r], mm);
      float p = (sv <= -1e37f) ? 0.f : __expf(sv - mnew);
      float psum = p;
      for (int off = 32; off > 0; off >>= 1) psum += __shfl_xor(psum, off);
      float alpha = __expf(m_run[r] - mnew);
      l_run[r] = l_run[r] * alpha + psum;
      acc[r] *= alpha;
      m_run[r] = mnew;
      ps[wid][lane][r] = p;
    }
    __syncthreads();  // ps visibility + keep phases aligned

    // accumulate: lane = d
    for (int j = 0; j < 64; ++j) {
      float vv = bf2f(Vt[j * 64 + lane]);
      float4 pv = *(const float4*)&ps[wid][j][0];
      acc[0] += pv.x * vv;
      acc[1] += pv.y * vv;
      acc[2] += pv.z * vv;
      acc[3] += pv.w * vv;
    }
  }
  for (int r = 0; r < 4; ++r)
    o[(rowbase + s0 + r) * (size_t)(HQ * DH) + h * DH + lane] = f2bf(acc[r] / l_run[r]);
}

// ---------------- SiLU(g) * u on fused [tok][GUN] buffer, writes gate half ----------------
__global__ __launch_bounds__(256) void silu_mul_kernel(u16* __restrict__ gu) {
  int idx = blockIdx.x * 256 + threadIdx.x;
  if (idx >= NTOK * (FFI / 2)) return;
  int row = idx / (FFI / 2), c = idx % (FFI / 2);
  size_t gp = (size_t)row * GUN + c * 2;
  u32 gv = *(const u32*)&gu[gp];
  u32 uv = *(const u32*)&gu[gp + FFI];
  float g0 = bf2f((u16)(gv & 0xffffu)), g1 = bf2f((u16)(gv >> 16));
  float u0 = bf2f((u16)(uv & 0xffffu)), u1 = bf2f((u16)(uv >> 16));
  float r0 = g0 / (1.f + __expf(-g0)) * u0;
  float r1 = g1 / (1.f + __expf(-g1)) * u1;
  *(u32*)&gu[gp] = (u32)f2bf(r0) | ((u32)f2bf(r1) << 16);
}

extern "C" void kernel_launch(void* const* d_in, const int* in_sizes, int n_in,
                              void* d_out, int out_size, void* d_ws, size_t ws_size,
                              hipStream_t stream) {
  const float* embeds = (const float*)d_in[0];
  const int*   tt     = (const int*)d_in[1];
  const float* amask  = (const float*)d_in[2];
  const float* wq  = (const float*)d_in[3];
  const float* bq  = (const float*)d_in[4];
  const float* wk  = (const float*)d_in[5];
  const float* bk  = (const float*)d_in[6];
  const float* wv  = (const float*)d_in[7];
  const float* bv  = (const float*)d_in[8];
  const float* wo  = (const float*)d_in[9];
  const float* wg  = (const float*)d_in[10];
  const float* wu  = (const float*)d_in[11];
  const float* wd  = (const float*)d_in[12];
  const float* ln1 = (const float*)d_in[13];
  const float* ln2 = (const float*)d_in[14];
  const float* lnf = (const float*)d_in[15];

  float* x = (float*)d_out;  // residual stream lives in d_out (fp32)
  char* ws = (char*)d_ws;
  u16* h_bf = (u16*)(ws + 0);          // [NTOK][896] bf16
  u16* qkvb = (u16*)(ws + 7340032);    // [NTOK][1152] bf16 fused q|k|v
  u16* ob   = (u16*)(ws + 16777216);   // [NTOK][896] bf16 attn out
  u16* gub  = (u16*)(ws + 24117248);   // [NTOK][9728] bf16 fused gate|up
  u16* wqT  = (u16*)(ws + 103809024);  // [896][896]   -- wqT|wkT|wvT contiguous = [1152][896]
  u16* wkT  = (u16*)(ws + 105414656);  // [128][896]
  u16* wvT  = (u16*)(ws + 105644032);  // [128][896]
  u16* woT  = (u16*)(ws + 105873408);  // [896][896]
  u16* wgT  = (u16*)(ws + 107479040);  // [4864][896]  -- wgT|wuT contiguous = [9728][896]
  u16* wuT  = (u16*)(ws + 116195328);  // [4864][896]
  u16* wdT  = (u16*)(ws + 124911616);  // [896][4864]

  hipMemcpyAsync(x, embeds, (size_t)NTOK * D * sizeof(float),
                 hipMemcpyDeviceToDevice, stream);

  for (int l = 0; l < NLAYER; ++l) {
    transpose_bf16_kernel<<<dim3(28, 28), 256, 0, stream>>>(wq + (size_t)l * 896 * 896, wqT, 896, 896);
    transpose_bf16_kernel<<<dim3(4, 28), 256, 0, stream>>>(wk + (size_t)l * 896 * 128, wkT, 896, 128);
    transpose_bf16_kernel<<<dim3(4, 28), 256, 0, stream>>>(wv + (size_t)l * 896 * 128, wvT, 896, 128);
    transpose_bf16_kernel<<<dim3(28, 28), 256, 0, stream>>>(wo + (size_t)l * 896 * 896, woT, 896, 896);
    transpose_bf16_kernel<<<dim3(152, 28), 256, 0, stream>>>(wg + (size_t)l * 896 * 4864, wgT, 896, 4864);
    transpose_bf16_kernel<<<dim3(152, 28), 256, 0, stream>>>(wu + (size_t)l * 896 * 4864, wuT, 896, 4864);
    transpose_bf16_kernel<<<dim3(28, 152), 256, 0, stream>>>(wd + (size_t)l * 4864 * 896, wdT, 4864, 896);

    rmsnorm_bf16_kernel<<<NTOK, 256, 0, stream>>>(x, ln1 + (size_t)l * D, h_bf);

    gemm_kernel<2><<<dim3(32, QKVN / 128), 256, 0, stream>>>(
        h_bf, D, wqT, bq + (size_t)l * 896, bk + (size_t)l * 128, bv + (size_t)l * 128,
        qkvb, QKVN, D);

    rope_kernel<<<NTOK * HQ * 32 / 256, 256, 0, stream>>>(qkvb, HQ, QKVN, 0, NTOK * HQ * 32);
    rope_kernel<<<NTOK * HKV * 32 / 256, 256, 0, stream>>>(qkvb, HKV, QKVN, KOFF, NTOK * HKV * 32);

    attn_kernel<<<dim3(SEQ / 16, HQ, BATCH), 256, 0, stream>>>(qkvb, tt, amask, ob);

    gemm_kernel<1><<<dim3(32, D / 128), 256, 0, stream>>>(
        ob, D, woT, nullptr, nullptr, nullptr, x, D, D);

    rmsnorm_bf16_kernel<<<NTOK, 256, 0, stream>>>(x, ln2 + (size_t)l * D, h_bf);

    gemm_kernel<0><<<dim3(32, GUN / 128), 256, 0, stream>>>(
        h_bf, D, wgT, nullptr, nullptr, nullptr, gub, GUN, D);

    silu_mul_kernel<<<(NTOK * (FFI / 2) + 255) / 256, 256, 0, stream>>>(gub);

    gemm_kernel<1><<<dim3(32, D / 128), 256, 0, stream>>>(
        gub, GUN, wdT, nullptr, nullptr, nullptr, x, D, FFI);
  }

  rmsnorm_f32_kernel<<<NTOK, 256, 0, stream>>>(x, lnf);
}

// Round 2
// 13508.186 us; speedup vs baseline: 5.3996x; 5.3996x over previous
//
#include <hip/hip_runtime.h>

#define D 896
#define NLAYER 24
#define HQ 14
#define HKV 2
#define DH 64
#define FFI 4864
#define BATCH 2
#define SEQ 2048
#define NTOK (BATCH*SEQ)
#define QKVN (HQ*DH + 2*HKV*DH)   /* 1152 */
#define KOFF (HQ*DH)              /* 896  */
#define VOFF (HQ*DH + HKV*DH)     /* 1024 */
#define GUN (2*FFI)               /* 9728 */

typedef unsigned short u16;
typedef unsigned int u32;
typedef __attribute__((ext_vector_type(8))) __bf16 bf16x8;
typedef __attribute__((ext_vector_type(4))) float f32x4;

__device__ __forceinline__ float bf2f(u16 u) {
  union { u32 u; float f; } v; v.u = ((u32)u) << 16; return v.f;
}
__device__ __forceinline__ u16 f2bf(float f) {
  union { float f; u32 u; } v; v.f = f;
  u32 r = v.u + 0x7fffu + ((v.u >> 16) & 1u);
  return (u16)(r >> 16);
}

// ---------------- RMSNorm: fp32 in -> bf16 out ----------------
__global__ __launch_bounds__(256) void rmsnorm_bf16_kernel(
    const float* __restrict__ x, const float* __restrict__ w, u16* __restrict__ out) {
  int row = blockIdx.x, t = threadIdx.x;
  const float* xr = x + (size_t)row * D;
  float4 xv = make_float4(0.f, 0.f, 0.f, 0.f);
  if (t < 224) xv = *(const float4*)(xr + t * 4);
  float ss = xv.x*xv.x + xv.y*xv.y + xv.z*xv.z + xv.w*xv.w;
  for (int off = 32; off > 0; off >>= 1) ss += __shfl_xor(ss, off);
  __shared__ float red[4];
  if ((t & 63) == 0) red[t >> 6] = ss;
  __syncthreads();
  float rstd = rsqrtf((red[0] + red[1] + red[2] + red[3]) * (1.0f / D) + 1e-6f);
  if (t < 224) {
    float4 wv = *(const float4*)(w + t * 4);
    u32 p0 = (u32)f2bf(xv.x*rstd*wv.x) | ((u32)f2bf(xv.y*rstd*wv.y) << 16);
    u32 p1 = (u32)f2bf(xv.z*rstd*wv.z) | ((u32)f2bf(xv.w*rstd*wv.w) << 16);
    uint2 ov; ov.x = p0; ov.y = p1;
    *(uint2*)(out + (size_t)row * D + t * 4) = ov;
  }
}

// ---------------- Final RMSNorm: fp32 in-place ----------------
__global__ __launch_bounds__(256) void rmsnorm_f32_kernel(
    float* __restrict__ x, const float* __restrict__ w) {
  int row = blockIdx.x, t = threadIdx.x;
  float* xr = x + (size_t)row * D;
  float4 xv = make_float4(0.f, 0.f, 0.f, 0.f);
  if (t < 224) xv = *(const float4*)(xr + t * 4);
  float ss = xv.x*xv.x + xv.y*xv.y + xv.z*xv.z + xv.w*xv.w;
  for (int off = 32; off > 0; off >>= 1) ss += __shfl_xor(ss, off);
  __shared__ float red[4];
  if ((t & 63) == 0) red[t >> 6] = ss;
  __syncthreads();
  float rstd = rsqrtf((red[0] + red[1] + red[2] + red[3]) * (1.0f / D) + 1e-6f);
  if (t < 224) {
    float4 wv = *(const float4*)(w + t * 4);
    float4 ov = make_float4(xv.x*rstd*wv.x, xv.y*rstd*wv.y, xv.z*rstd*wv.z, xv.w*rstd*wv.w);
    *(float4*)(xr + t * 4) = ov;
  }
}

// ------------- Transpose fp32 [R][C] -> bf16 [C][R] -------------
__global__ __launch_bounds__(256) void transpose_bf16_kernel(
    const float* __restrict__ src, u16* __restrict__ dst, int R, int C) {
  __shared__ float tile[32][33];
  int c0 = blockIdx.x * 32, r0 = blockIdx.y * 32;
  int tx = threadIdx.x & 31, ty = threadIdx.x >> 5;  // ty 0..7
  for (int i = 0; i < 4; ++i)
    tile[ty + i * 8][tx] = src[(size_t)(r0 + ty + i * 8) * C + c0 + tx];
  __syncthreads();
  for (int i = 0; i < 4; ++i)
    dst[(size_t)(c0 + ty + i * 8) * R + r0 + tx] = f2bf(tile[tx][ty + i * 8]);
}

// ---------------- GEMM: C[M,N] = A[M,K](bf16) @ Bt[N,K]^T(bf16) ----------------
// MODE 0: bf16 out (+optional bias b0)
// MODE 1: fp32 out += (residual add)
// MODE 2: bf16 out, fused-QKV 3-way bias (b0 cols<896, b1 <1024, b2 rest)
template <int MODE>
__global__ __launch_bounds__(256) void gemm_kernel(
    const u16* __restrict__ A, int lda, const u16* __restrict__ Bt,
    const float* __restrict__ b0, const float* __restrict__ b1, const float* __restrict__ b2,
    void* __restrict__ outp, int N, int K) {
  __shared__ __align__(16) u16 As[128 * 40];
  __shared__ __align__(16) u16 Bs[128 * 40];
  const int tid = threadIdx.x;
  const int lane = tid & 63, wid = tid >> 6;
  const int wm = wid >> 1, wn = wid & 1;
  const int quad = lane >> 4, l16 = lane & 15;
  const int m0 = blockIdx.x * 128, n0 = blockIdx.y * 128;
  const int r0 = tid >> 2, seg = tid & 3;

  f32x4 acc[4][4];
  for (int i = 0; i < 4; ++i)
    for (int j = 0; j < 4; ++j) acc[i][j] = (f32x4){0.f, 0.f, 0.f, 0.f};

  for (int kt = 0; kt < K; kt += 32) {
    for (int i = 0; i < 2; ++i) {
      int row = r0 + i * 64;
      *(uint4*)&As[row * 40 + seg * 8] =
          *(const uint4*)&A[(size_t)(m0 + row) * lda + kt + seg * 8];
      *(uint4*)&Bs[row * 40 + seg * 8] =
          *(const uint4*)&Bt[(size_t)(n0 + row) * K + kt + seg * 8];
    }
    __syncthreads();
    bf16x8 af[4], bf[4];
    for (int mi = 0; mi < 4; ++mi)
      af[mi] = *(const bf16x8*)&As[(wm * 64 + mi * 16 + l16) * 40 + quad * 8];
    for (int ni = 0; ni < 4; ++ni)
      bf[ni] = *(const bf16x8*)&Bs[(wn * 64 + ni * 16 + l16) * 40 + quad * 8];
    for (int mi = 0; mi < 4; ++mi)
      for (int ni = 0; ni < 4; ++ni)
        acc[mi][ni] = __builtin_amdgcn_mfma_f32_16x16x32_bf16(af[mi], bf[ni], acc[mi][ni], 0, 0, 0);
    __syncthreads();
  }

  for (int mi = 0; mi < 4; ++mi) {
    int rowb = m0 + wm * 64 + mi * 16 + quad * 4;
    for (int ni = 0; ni < 4; ++ni) {
      int col = n0 + wn * 64 + ni * 16 + l16;
      float bvv = 0.f;
      if (MODE == 0 && b0 != nullptr) bvv = b0[col];
      if (MODE == 2) bvv = (col < KOFF) ? b0[col] : (col < VOFF) ? b1[col - KOFF] : b2[col - VOFF];
      for (int r = 0; r < 4; ++r) {
        if (MODE == 1)
          ((float*)outp)[(size_t)(rowb + r) * N + col] += acc[mi][ni][r];
        else
          ((u16*)outp)[(size_t)(rowb + r) * N + col] = f2bf(acc[mi][ni][r] + bvv);
      }
    }
  }
}

// ---------------- RoPE in-place on bf16 (q or k region of fused qkv) ----------------
__global__ __launch_bounds__(256) void rope_kernel(
    u16* __restrict__ x, int H, int rowStride, int colOff, int total) {
  int gid = blockIdx.x * 256 + threadIdx.x;
  if (gid >= total) return;
  int i = gid & 31;
  int rem = gid >> 5;
  int h = rem % H;
  int tok = rem / H;
  int s = tok & (SEQ - 1);
  size_t base = (size_t)tok * rowStride + colOff + h * DH;
  float x1 = bf2f(x[base + i]), x2 = bf2f(x[base + i + 32]);
  float inv = exp2f((float)i * (-2.0f / DH) * 19.931568569324174f);  // theta^(-2i/DH)
  float ang = (float)s * inv;
  float c, sn;
  sincosf(ang, &sn, &c);
  x[base + i]      = f2bf(x1 * c - x2 * sn);
  x[base + i + 32] = f2bf(x2 * c + x1 * sn);
}

// ---------------- MFMA flash attention ----------------
// Block: 64 q rows for one (b,h). 4 waves, each 16 q rows.
// K-tiles of 64 keys: S = Q@K^T (8 mfma), online softmax, O += P@V (8 mfma).
#define KST 72  /* LDS row stride (u16) for K/Vt/P tiles: 144B, 16B-aligned, 2-way banks */
__global__ __launch_bounds__(256) void attn_kernel(
    const u16* __restrict__ qkv, const int* __restrict__ tt,
    const float* __restrict__ mask, u16* __restrict__ o) {
  const int tid = threadIdx.x, wid = tid >> 6, lane = tid & 63;
  const int l16 = lane & 15, quad = lane >> 4;
  const int b = blockIdx.z, h = blockIdx.y;
  const int hkv = h / (HQ / HKV);
  const int qb = blockIdx.x * 64;
  const size_t rowbase = (size_t)b * SEQ;

  __shared__ __align__(16) u16 Ks[64 * KST];       // K natural [key][dh]
  __shared__ __align__(16) u16 Vts[64 * KST];      // V transposed [dh][key]
  __shared__ __align__(16) u16 Ps[4][16 * KST];    // per-wave P [q][key]
  __shared__ int kcs[64];                          // key class: 0/1 token type, 2 = padded out

  // Q fragments (A layout: m=l16, k=quad*8+j), rows qb+wid*16+l16
  const int qrow = qb + wid * 16 + l16;
  const bf16x8 qf0 = *(const bf16x8*)&qkv[(rowbase + qrow) * QKVN + h * DH + quad * 8];
  const bf16x8 qf1 = *(const bf16x8*)&qkv[(rowbase + qrow) * QKVN + h * DH + 32 + quad * 8];

  int tq[4];
  for (int r = 0; r < 4; ++r) tq[r] = tt[rowbase + qb + wid * 16 + quad * 4 + r];

  float mrun[4], lrun[4];
  f32x4 oacc[4];
  for (int r = 0; r < 4; ++r) { mrun[r] = -3e38f; lrun[r] = 0.f; }
  for (int ni = 0; ni < 4; ++ni) oacc[ni] = (f32x4){0.f, 0.f, 0.f, 0.f};

  for (int kt = 0; kt < SEQ / 64; ++kt) {
    // ---- stage K tile [key][dh], coalesced ----
    {
      int key = tid >> 2;
      size_t roff = (rowbase + kt * 64 + key) * QKVN + KOFF + hkv * DH;
      for (int i = 0; i < 2; ++i) {
        int seg = (tid & 3) + i * 4;
        *(uint4*)&Ks[key * KST + seg * 8] = *(const uint4*)&qkv[roff + seg * 8];
      }
    }
    // ---- stage V transposed [dh][key], 2 keys packed per u32 write ----
    {
      int kp = tid & 31, seg = tid >> 5;  // kp: key pair, seg: dh octet
      size_t ra = (rowbase + kt * 64 + kp * 2) * QKVN + VOFF + hkv * DH + seg * 8;
      uint4 va = *(const uint4*)&qkv[ra];
      uint4 vb2 = *(const uint4*)&qkv[ra + QKVN];
      const u16* pa_ = (const u16*)&va;
      const u16* pb_ = (const u16*)&vb2;
      for (int j = 0; j < 8; ++j)
        *(u32*)&Vts[(seg * 8 + j) * KST + kp * 2] = (u32)pa_[j] | ((u32)pb_[j] << 16);
    }
    if (tid < 64) {
      int kidx = kt * 64 + tid;
      float mk = mask[rowbase + kidx];
      kcs[tid] = (mk == 0.f) ? 2 : tt[rowbase + kidx];
    }
    __syncthreads();

    // ---- S = Q @ K^T ----
    f32x4 sac[4];
    for (int ni = 0; ni < 4; ++ni) sac[ni] = (f32x4){0.f, 0.f, 0.f, 0.f};
    for (int ni = 0; ni < 4; ++ni) {
      bf16x8 kf0 = *(const bf16x8*)&Ks[(ni * 16 + l16) * KST + quad * 8];
      bf16x8 kf1 = *(const bf16x8*)&Ks[(ni * 16 + l16) * KST + 32 + quad * 8];
      sac[ni] = __builtin_amdgcn_mfma_f32_16x16x32_bf16(qf0, kf0, sac[ni], 0, 0, 0);
      sac[ni] = __builtin_amdgcn_mfma_f32_16x16x32_bf16(qf1, kf1, sac[ni], 0, 0, 0);
    }

    int kc[4];
    for (int ni = 0; ni < 4; ++ni) kc[ni] = kcs[ni * 16 + l16];

    // ---- online softmax (C layout: row=quad*4+r, col=ni*16+l16) ----
    float pv[4][4];  // [ni][r]
    for (int r = 0; r < 4; ++r) {
      int qi = qb + wid * 16 + quad * 4 + r;
      float sv[4];
      float mloc = -3e38f;
      for (int ni = 0; ni < 4; ++ni) {
        int kidx = kt * 64 + ni * 16 + l16;
        bool allowed = (tq[r] == 0) ? (kc[ni] == 0)
                                    : (kc[ni] == 0 || (kc[ni] == 1 && kidx <= qi));
        sv[ni] = allowed ? sac[ni][r] * 0.125f : -3e38f;
        mloc = fmaxf(mloc, sv[ni]);
      }
      for (int off = 1; off < 16; off <<= 1) mloc = fmaxf(mloc, __shfl_xor(mloc, off));
      float mnew = fmaxf(mrun[r], mloc);
      float rs = 0.f;
      for (int ni = 0; ni < 4; ++ni) {
        float p = (sv[ni] <= -1e37f) ? 0.f : __expf(sv[ni] - mnew);
        pv[ni][r] = p;
        rs += p;
      }
      for (int off = 1; off < 16; off <<= 1) rs += __shfl_xor(rs, off);
      float alpha = __expf(mrun[r] - mnew);
      lrun[r] = lrun[r] * alpha + rs;
      mrun[r] = mnew;
      for (int ni = 0; ni < 4; ++ni) oacc[ni][r] *= alpha;
    }

    // ---- P -> bf16 -> per-wave LDS, reload as A fragments ----
    for (int r = 0; r < 4; ++r)
      for (int ni = 0; ni < 4; ++ni)
        Ps[wid][(quad * 4 + r) * KST + ni * 16 + l16] = f2bf(pv[ni][r]);
    asm volatile("s_waitcnt lgkmcnt(0)" ::: "memory");

    for (int kk = 0; kk < 2; ++kk) {
      bf16x8 pf = *(const bf16x8*)&Ps[wid][l16 * KST + kk * 32 + quad * 8];
      for (int ni = 0; ni < 4; ++ni) {
        bf16x8 vf = *(const bf16x8*)&Vts[(ni * 16 + l16) * KST + kk * 32 + quad * 8];
        oacc[ni] = __builtin_amdgcn_mfma_f32_16x16x32_bf16(pf, vf, oacc[ni], 0, 0, 0);
      }
    }
    __syncthreads();
  }

  for (int r = 0; r < 4; ++r) {
    float inv = 1.f / lrun[r];
    size_t row = rowbase + qb + wid * 16 + quad * 4 + r;
    for (int ni = 0; ni < 4; ++ni)
      o[row * (size_t)(HQ * DH) + h * DH + ni * 16 + l16] = f2bf(oacc[ni][r] * inv);
  }
}

// ---------------- SiLU(g) * u on fused [tok][GUN] buffer, writes gate half ----------------
__global__ __launch_bounds__(256) void silu_mul_kernel(u16* __restrict__ gu) {
  int idx = blockIdx.x * 256 + threadIdx.x;
  if (idx >= NTOK * (FFI / 2)) return;
  int row = idx / (FFI / 2), c = idx % (FFI / 2);
  size_t gp = (size_t)row * GUN + c * 2;
  u32 gv = *(const u32*)&gu[gp];
  u32 uv = *(const u32*)&gu[gp + FFI];
  float g0 = bf2f((u16)(gv & 0xffffu)), g1 = bf2f((u16)(gv >> 16));
  float u0 = bf2f((u16)(uv & 0xffffu)), u1 = bf2f((u16)(uv >> 16));
  float r0 = g0 / (1.f + __expf(-g0)) * u0;
  float r1 = g1 / (1.f + __expf(-g1)) * u1;
  *(u32*)&gu[gp] = (u32)f2bf(r0) | ((u32)f2bf(r1) << 16);
}

extern "C" void kernel_launch(void* const* d_in, const int* in_sizes, int n_in,
                              void* d_out, int out_size, void* d_ws, size_t ws_size,
                              hipStream_t stream) {
  const float* embeds = (const float*)d_in[0];
  const int*   tt     = (const int*)d_in[1];
  const float* amask  = (const float*)d_in[2];
  const float* wq  = (const float*)d_in[3];
  const float* bq  = (const float*)d_in[4];
  const float* wk  = (const float*)d_in[5];
  const float* bk  = (const float*)d_in[6];
  const float* wv  = (const float*)d_in[7];
  const float* bv  = (const float*)d_in[8];
  const float* wo  = (const float*)d_in[9];
  const float* wg  = (const float*)d_in[10];
  const float* wu  = (const float*)d_in[11];
  const float* wd  = (const float*)d_in[12];
  const float* ln1 = (const float*)d_in[13];
  const float* ln2 = (const float*)d_in[14];
  const float* lnf = (const float*)d_in[15];

  float* x = (float*)d_out;  // residual stream lives in d_out (fp32)
  char* ws = (char*)d_ws;
  u16* h_bf = (u16*)(ws + 0);          // [NTOK][896] bf16
  u16* qkvb = (u16*)(ws + 7340032);    // [NTOK][1152] bf16 fused q|k|v
  u16* ob   = (u16*)(ws + 16777216);   // [NTOK][896] bf16 attn out
  u16* gub  = (u16*)(ws + 24117248);   // [NTOK][9728] bf16 fused gate|up
  u16* wqT  = (u16*)(ws + 103809024);  // [896][896]   -- wqT|wkT|wvT contiguous = [1152][896]
  u16* wkT  = (u16*)(ws + 105414656);  // [128][896]
  u16* wvT  = (u16*)(ws + 105644032);  // [128][896]
  u16* woT  = (u16*)(ws + 105873408);  // [896][896]
  u16* wgT  = (u16*)(ws + 107479040);  // [4864][896]  -- wgT|wuT contiguous = [9728][896]
  u16* wuT  = (u16*)(ws + 116195328);  // [4864][896]
  u16* wdT  = (u16*)(ws + 124911616);  // [896][4864]

  hipMemcpyAsync(x, embeds, (size_t)NTOK * D * sizeof(float),
                 hipMemcpyDeviceToDevice, stream);

  for (int l = 0; l < NLAYER; ++l) {
    transpose_bf16_kernel<<<dim3(28, 28), 256, 0, stream>>>(wq + (size_t)l * 896 * 896, wqT, 896, 896);
    transpose_bf16_kernel<<<dim3(4, 28), 256, 0, stream>>>(wk + (size_t)l * 896 * 128, wkT, 896, 128);
    transpose_bf16_kernel<<<dim3(4, 28), 256, 0, stream>>>(wv + (size_t)l * 896 * 128, wvT, 896, 128);
    transpose_bf16_kernel<<<dim3(28, 28), 256, 0, stream>>>(wo + (size_t)l * 896 * 896, woT, 896, 896);
    transpose_bf16_kernel<<<dim3(152, 28), 256, 0, stream>>>(wg + (size_t)l * 896 * 4864, wgT, 896, 4864);
    transpose_bf16_kernel<<<dim3(152, 28), 256, 0, stream>>>(wu + (size_t)l * 896 * 4864, wuT, 896, 4864);
    transpose_bf16_kernel<<<dim3(28, 152), 256, 0, stream>>>(wd + (size_t)l * 4864 * 896, wdT, 4864, 896);

    rmsnorm_bf16_kernel<<<NTOK, 256, 0, stream>>>(x, ln1 + (size_t)l * D, h_bf);

    gemm_kernel<2><<<dim3(32, QKVN / 128), 256, 0, stream>>>(
        h_bf, D, wqT, bq + (size_t)l * 896, bk + (size_t)l * 128, bv + (size_t)l * 128,
        qkvb, QKVN, D);

    rope_kernel<<<NTOK * HQ * 32 / 256, 256, 0, stream>>>(qkvb, HQ, QKVN, 0, NTOK * HQ * 32);
    rope_kernel<<<NTOK * HKV * 32 / 256, 256, 0, stream>>>(qkvb, HKV, QKVN, KOFF, NTOK * HKV * 32);

    attn_kernel<<<dim3(SEQ / 64, HQ, BATCH), 256, 0, stream>>>(qkvb, tt, amask, ob);

    gemm_kernel<1><<<dim3(32, D / 128), 256, 0, stream>>>(
        ob, D, woT, nullptr, nullptr, nullptr, x, D, D);

    rmsnorm_bf16_kernel<<<NTOK, 256, 0, stream>>>(x, ln2 + (size_t)l * D, h_bf);

    gemm_kernel<0><<<dim3(32, GUN / 128), 256, 0, stream>>>(
        h_bf, D, wgT, nullptr, nullptr, nullptr, gub, GUN, D);

    silu_mul_kernel<<<(NTOK * (FFI / 2) + 255) / 256, 256, 0, stream>>>(gub);

    gemm_kernel<1><<<dim3(32, D / 128), 256, 0, stream>>>(
        gub, GUN, wdT, nullptr, nullptr, nullptr, x, D, FFI);
  }

  rmsnorm_f32_kernel<<<NTOK, 256, 0, stream>>>(x, lnf);
}